// Round 1
// baseline (21386.237 us; speedup 1.0000x reference)
//
#include <hip/hip_runtime.h>

#define TT 512
#define BH 65536            // B*H elements (64*1024)
#define NBLK 256

typedef unsigned short u16;
typedef __attribute__((ext_vector_type(8))) __bf16 bf16x8;
typedef __attribute__((ext_vector_type(4))) float f32x4;
typedef __attribute__((ext_vector_type(4))) float float4_t;

// workspace byte offsets
#define WS_XBF   0ull
#define WS_H1    67108864ull                 // x_bf16: 512*64*1024*2 B
#define WS_H2    (WS_H1 + 262144ull)         // 2 slots * 64*1024 * 2 B
#define WS_BAR   (WS_H2 + 262144ull)

#define LDS_BYTES 132096                     // 2 * 32 rows * 1032 elems * 2 B

__device__ __forceinline__ u16 f2bf(float f) {
  unsigned u = __builtin_bit_cast(unsigned, f);
  u += 0x7fffu + ((u >> 16) & 1u);
  return (u16)(u >> 16);
}

__device__ __forceinline__ float sigm(float x) { return 1.0f / (1.0f + __expf(-x)); }
__device__ __forceinline__ float tanh_fast(float x) { return 1.0f - 2.0f / (__expf(2.0f * x) + 1.0f); }

__global__ __launch_bounds__(256) void cast_x_kernel(const float* __restrict__ x, u16* __restrict__ xbf) {
  unsigned i = (blockIdx.x * 256u + threadIdx.x) * 4u;
  float4_t v = *(const float4_t*)(x + i);
  unsigned p0 = (unsigned)f2bf(v.x) | ((unsigned)f2bf(v.y) << 16);
  unsigned p1 = (unsigned)f2bf(v.z) | ((unsigned)f2bf(v.w) << 16);
  uint2 p; p.x = p0; p.y = p1;
  *(uint2*)(xbf + i) = p;
}

__global__ __launch_bounds__(256) void init_kernel(const float* __restrict__ h0,
                                                   u16* __restrict__ h1s, u16* __restrict__ h2s,
                                                   int* __restrict__ bar) {
  unsigned idx = blockIdx.x * 256u + threadIdx.x;   // < 131072
  unsigned l = idx >> 16;
  unsigned pos = idx & 65535u;
  u16* dst = (l == 0 ? h1s : h2s) + BH + pos;       // slot 1 = "h[-1]"
  *dst = f2bf(h0[idx]);
  if (idx < 2) bar[idx] = 0;
}

// 256 blocks: 0..127 layer0 (step t=it), 128..255 layer1 (step t=it-1).
// Each block: 8 hidden cols -> 32 gate cols, weights LDS-resident, c in regs.
__global__ __launch_bounds__(256, 1) void lstm_kernel(
    const float* __restrict__ Wih, const float* __restrict__ Whh,
    const float* __restrict__ bias, const float* __restrict__ c0,
    const u16* __restrict__ xbf,
    u16* __restrict__ h1s, u16* __restrict__ h2s,
    float* __restrict__ out, int* __restrict__ bar)
{
  extern __shared__ __align__(16) char smem_raw[];
  u16* lw = (u16*)smem_raw;                 // [2][32][1032] bf16, +8 pad per row
  const int tid = threadIdx.x;
  const int bid = blockIdx.x;
  const int layer = bid >> 7;
  const int lb = bid & 127;
  const int jbase = lb * 8;

  // ---- stage weight slices into LDS (fp32 -> bf16), rows n = gate*8 + jj ----
  const float* WihL = Wih + (size_t)layer * 4096 * 1024;
  const float* WhhL = Whh + (size_t)layer * 4096 * 1024;
  for (int idx = tid; idx < 8192; idx += 256) {
    int n = idx >> 8;                       // 0..31
    int k4 = (idx & 255) * 4;
    int gate = n >> 3, jj = n & 7;
    size_t grow = (size_t)(gate * 1024 + jbase + jj) * 1024 + k4;
    float4_t a = *(const float4_t*)(WihL + grow);
    float4_t b = *(const float4_t*)(WhhL + grow);
    u16* d0 = lw + n * 1032 + k4;
    u16* d1 = lw + 33024 + n * 1032 + k4;   // Whh block at +32*1032
    d0[0] = f2bf(a.x); d0[1] = f2bf(a.y); d0[2] = f2bf(a.z); d0[3] = f2bf(a.w);
    d1[0] = f2bf(b.x); d1[1] = f2bf(b.y); d1[2] = f2bf(b.z); d1[3] = f2bf(b.w);
  }

  const int lane = tid & 63;
  const int w = tid >> 6;                   // wave id: M-tile
  const int q = lane >> 4;                  // quad
  const int ln = lane & 15;
  const int arow = w * 16 + ln;             // batch row for A-frag loads
  const int koff = q * 8;
  const int jj = ln & 7;
  const bool act = ln < 8;                  // epilogue-active lanes
  const int col = jbase + jj;               // hidden column
  const int mrow0 = w * 16 + q * 4;         // C-frag rows mrow0 + r

  const float* bL = bias + layer * 4096;
  const float bn0 = bL[(ln >> 3) * 1024 + jbase + jj];        // i/f bias (col n=ln)
  const float bn1 = bL[(2 + (ln >> 3)) * 1024 + jbase + jj];  // g/o bias (col n=16+ln)

  float c[4];
  {
    const float* c0L = c0 + (size_t)layer * BH;
#pragma unroll
    for (int r = 0; r < 4; ++r) c[r] = c0L[(mrow0 + r) * 1024 + col];
  }

  u16* mySlot = (layer == 0) ? h1s : h2s;
  const size_t OUT_HN = (size_t)TT * BH;
  const size_t OUT_CN = OUT_HN + 2 * BH;

  // per-lane LDS base pointers for B-fragments
  const u16* bW0 = lw + ln * 1032 + koff;          // Wih, N-tile 0 (gates i,f)
  const u16* bW1 = lw + (16 + ln) * 1032 + koff;   // Wih, N-tile 1 (gates g,o)
  const u16* bH0 = bW0 + 33024;                    // Whh
  const u16* bH1 = bW1 + 33024;

  __syncthreads();

  for (int it = 0; it <= TT; ++it) {
    const int t = (layer == 0) ? it : (it - 1);
    if (t >= 0 && t < TT) {
      const u16* src0 = (layer == 0) ? (xbf + (size_t)t * BH)
                                     : (h1s + (size_t)(t & 1) * BH);
      const u16* src1 = mySlot + (size_t)((t - 1) & 1) * BH;
      const u16* a0p = src0 + arow * 1024 + koff;
      const u16* a1p = src1 + arow * 1024 + koff;

      f32x4 acc0 = {0.f, 0.f, 0.f, 0.f};
      f32x4 acc1 = {0.f, 0.f, 0.f, 0.f};
#pragma unroll 8
      for (int kc = 0; kc < 32; ++kc) {     // input projection (x_t or h1_t)
        bf16x8 a  = *(const bf16x8*)(a0p + kc * 32);
        bf16x8 b0 = *(const bf16x8*)(bW0 + kc * 32);
        bf16x8 b1 = *(const bf16x8*)(bW1 + kc * 32);
        acc0 = __builtin_amdgcn_mfma_f32_16x16x32_bf16(a, b0, acc0, 0, 0, 0);
        acc1 = __builtin_amdgcn_mfma_f32_16x16x32_bf16(a, b1, acc1, 0, 0, 0);
      }
#pragma unroll 8
      for (int kc = 0; kc < 32; ++kc) {     // recurrent projection (h_{t-1})
        bf16x8 a  = *(const bf16x8*)(a1p + kc * 32);
        bf16x8 b0 = *(const bf16x8*)(bH0 + kc * 32);
        bf16x8 b1 = *(const bf16x8*)(bH1 + kc * 32);
        acc0 = __builtin_amdgcn_mfma_f32_16x16x32_bf16(a, b0, acc0, 0, 0, 0);
        acc1 = __builtin_amdgcn_mfma_f32_16x16x32_bf16(a, b1, acc1, 0, 0, 0);
      }

      float g0[4], g1[4], f4[4], o4[4];
#pragma unroll
      for (int r = 0; r < 4; ++r) { g0[r] = acc0[r] + bn0; g1[r] = acc1[r] + bn1; }
#pragma unroll
      for (int r = 0; r < 4; ++r) { f4[r] = __shfl_down(g0[r], 8); o4[r] = __shfl_down(g1[r], 8); }

      if (act) {
        float hn[4];
#pragma unroll
        for (int r = 0; r < 4; ++r) {
          float iv = sigm(g0[r]);           // cols 0..7   : i
          float fv = sigm(f4[r]);           // cols 8..15  : f (shuffled)
          float gv = tanh_fast(g1[r]);      // cols 16..23 : g
          float ov = sigm(o4[r]);           // cols 24..31 : o (shuffled)
          c[r] = fv * c[r] + iv * gv;
          hn[r] = ov * tanh_fast(c[r]);
        }
        u16* hdst = mySlot + (size_t)(t & 1) * BH;
#pragma unroll
        for (int r = 0; r < 4; ++r) hdst[(mrow0 + r) * 1024 + col] = f2bf(hn[r]);
        if (layer == 1) {
          float* od = out + (size_t)t * BH;
#pragma unroll
          for (int r = 0; r < 4; ++r) od[(mrow0 + r) * 1024 + col] = hn[r];
        }
        if (t == TT - 1) {
#pragma unroll
          for (int r = 0; r < 4; ++r) {
            out[OUT_HN + (size_t)layer * BH + (mrow0 + r) * 1024 + col] = hn[r];
            out[OUT_CN + (size_t)layer * BH + (mrow0 + r) * 1024 + col] = c[r];
          }
        }
      }
    }

    if (it < TT) {                           // grid barrier (monotone counter)
      __syncthreads();
      if (tid == 0) {
        __threadfence();
        int prev = __hip_atomic_fetch_add(&bar[0], 1, __ATOMIC_ACQ_REL, __HIP_MEMORY_SCOPE_AGENT);
        if (prev == (it + 1) * NBLK - 1) {
          __hip_atomic_store(&bar[1], it + 1, __ATOMIC_RELEASE, __HIP_MEMORY_SCOPE_AGENT);
        } else {
          while (__hip_atomic_load(&bar[1], __ATOMIC_ACQUIRE, __HIP_MEMORY_SCOPE_AGENT) < it + 1) {
            __builtin_amdgcn_s_sleep(2);
          }
        }
        __threadfence();
      }
      __syncthreads();
    }
  }
}

extern "C" void kernel_launch(void* const* d_in, const int* in_sizes, int n_in,
                              void* d_out, int out_size, void* d_ws, size_t ws_size,
                              hipStream_t stream) {
  const float* x    = (const float*)d_in[0];
  const float* Wih  = (const float*)d_in[1];
  const float* Whh  = (const float*)d_in[2];
  const float* bias = (const float*)d_in[3];
  const float* h0   = (const float*)d_in[4];
  const float* c0   = (const float*)d_in[5];
  float* out = (float*)d_out;
  char* ws = (char*)d_ws;
  u16* xbf = (u16*)(ws + WS_XBF);
  u16* h1s = (u16*)(ws + WS_H1);
  u16* h2s = (u16*)(ws + WS_H2);
  int* bar = (int*)(ws + WS_BAR);

  hipFuncSetAttribute((const void*)lstm_kernel,
                      hipFuncAttributeMaxDynamicSharedMemorySize, LDS_BYTES);

  cast_x_kernel<<<32768, 256, 0, stream>>>(x, xbf);
  init_kernel<<<512, 256, 0, stream>>>(h0, h1s, h2s, bar);
  lstm_kernel<<<NBLK, 256, LDS_BYTES, stream>>>(Wih, Whh, bias, c0, xbf, h1s, h2s, out, bar);
}

// Round 2
// 11102.663 us; speedup vs baseline: 1.9262x; 1.9262x over previous
//
#include <hip/hip_runtime.h>

#define TT 512
#define BH 65536            // B*H elements (64*1024)
#define NBLK 256

typedef unsigned short u16;
typedef __attribute__((ext_vector_type(8))) __bf16 bf16x8;
typedef __attribute__((ext_vector_type(4))) float f32x4;
typedef __attribute__((ext_vector_type(4))) float float4_t;

// workspace byte offsets
#define WS_XBF   0ull
#define WS_H1    67108864ull                 // x_bf16: 512*64*1024*2 B
#define WS_H2    (WS_H1 + 262144ull)         // 2 slots * 64*1024 * 2 B
#define WS_FLAGS (WS_H2 + 262144ull)         // 256 blocks * 32 ints (128 B apart)
#define WS_REL   (WS_FLAGS + 32768ull)       // release word, own line

#define LDS_BYTES 132096                     // 2 * 32 rows * 1032 elems * 2 B

__device__ __forceinline__ u16 f2bf(float f) {
  unsigned u = __builtin_bit_cast(unsigned, f);
  u += 0x7fffu + ((u >> 16) & 1u);
  return (u16)(u >> 16);
}

__device__ __forceinline__ float sigm(float x) { return 1.0f / (1.0f + __expf(-x)); }
__device__ __forceinline__ float tanh_fast(float x) { return 1.0f - 2.0f / (__expf(2.0f * x) + 1.0f); }

__global__ __launch_bounds__(256) void cast_x_kernel(const float* __restrict__ x, u16* __restrict__ xbf) {
  unsigned i = (blockIdx.x * 256u + threadIdx.x) * 4u;
  float4_t v = *(const float4_t*)(x + i);
  unsigned p0 = (unsigned)f2bf(v.x) | ((unsigned)f2bf(v.y) << 16);
  unsigned p1 = (unsigned)f2bf(v.z) | ((unsigned)f2bf(v.w) << 16);
  uint2 p; p.x = p0; p.y = p1;
  *(uint2*)(xbf + i) = p;
}

__global__ __launch_bounds__(256) void init_kernel(const float* __restrict__ h0,
                                                   u16* __restrict__ h1s, u16* __restrict__ h2s,
                                                   int* __restrict__ flags, int* __restrict__ rel) {
  unsigned idx = blockIdx.x * 256u + threadIdx.x;   // < 131072
  unsigned l = idx >> 16;
  unsigned pos = idx & 65535u;
  u16* dst = (l == 0 ? h1s : h2s) + BH + pos;       // slot 1 = "h[-1]"
  *dst = f2bf(h0[idx]);
  if (idx < 8192) flags[idx] = 0;
  if (idx == 0) rel[0] = 0;
}

// 256 blocks: 0..127 layer0 (step t=it), 128..255 layer1 (step t=it-1).
// Each block: 8 hidden cols -> 32 gate cols, weights LDS-resident, c in regs.
__global__ __launch_bounds__(256, 1) void lstm_kernel(
    const float* __restrict__ Wih, const float* __restrict__ Whh,
    const float* __restrict__ bias, const float* __restrict__ c0,
    const u16* __restrict__ xbf,
    u16* __restrict__ h1s, u16* __restrict__ h2s,
    float* __restrict__ out, int* __restrict__ flags, int* __restrict__ rel)
{
  extern __shared__ __align__(16) char smem_raw[];
  u16* lw = (u16*)smem_raw;                 // Wih[32][1032] then Whh[32][1032]
  const int tid = threadIdx.x;
  const int bid = blockIdx.x;
  const int layer = bid >> 7;
  const int lb = bid & 127;
  const int jbase = lb * 8;

  // ---- stage weight slices into LDS (fp32 -> bf16), rows n = gate*8 + jj ----
  const float* WihL = Wih + (size_t)layer * 4096 * 1024;
  const float* WhhL = Whh + (size_t)layer * 4096 * 1024;
  for (int idx = tid; idx < 8192; idx += 256) {
    int n = idx >> 8;                       // 0..31
    int k4 = (idx & 255) * 4;
    int gate = n >> 3, jj = n & 7;
    size_t grow = (size_t)(gate * 1024 + jbase + jj) * 1024 + k4;
    float4_t a = *(const float4_t*)(WihL + grow);
    float4_t b = *(const float4_t*)(WhhL + grow);
    u16* d0 = lw + n * 1032 + k4;
    u16* d1 = lw + 33024 + n * 1032 + k4;   // Whh block at +32*1032
    d0[0] = f2bf(a.x); d0[1] = f2bf(a.y); d0[2] = f2bf(a.z); d0[3] = f2bf(a.w);
    d1[0] = f2bf(b.x); d1[1] = f2bf(b.y); d1[2] = f2bf(b.z); d1[3] = f2bf(b.w);
  }

  const int lane = tid & 63;
  const int w = tid >> 6;                   // wave id: M-tile
  const int q = lane >> 4;                  // quad
  const int ln = lane & 15;
  const int arow = w * 16 + ln;             // batch row for A-frag loads
  const int koff = q * 8;
  const int jj = ln & 7;
  const bool act = ln < 8;                  // epilogue-active lanes
  const int col = jbase + jj;               // hidden column
  const int mrow0 = w * 16 + q * 4;         // C-frag rows mrow0 + r

  const float* bL = bias + layer * 4096;
  const float bn0 = bL[(ln >> 3) * 1024 + jbase + jj];        // i/f bias (col n=ln)
  const float bn1 = bL[(2 + (ln >> 3)) * 1024 + jbase + jj];  // g/o bias (col n=16+ln)

  float c[4];
  {
    const float* c0L = c0 + (size_t)layer * BH;
#pragma unroll
    for (int r = 0; r < 4; ++r) c[r] = c0L[(mrow0 + r) * 1024 + col];
  }

  u16* mySlot = (layer == 0) ? h1s : h2s;
  const size_t OUT_HN = (size_t)TT * BH;
  const size_t OUT_CN = OUT_HN + 2 * BH;

  // per-lane LDS base pointers for B-fragments
  const u16* bW0 = lw + ln * 1032 + koff;          // Wih, N-tile 0 (gates i,f)
  const u16* bW1 = lw + (16 + ln) * 1032 + koff;   // Wih, N-tile 1 (gates g,o)
  const u16* bH0 = bW0 + 33024;                    // Whh
  const u16* bH1 = bW1 + 33024;

  __syncthreads();

  for (int it = 0; it <= TT; ++it) {
    const int t = (layer == 0) ? it : (it - 1);
    if (t >= 0 && t < TT) {
      const u16* src0 = (layer == 0) ? (xbf + (size_t)t * BH)
                                     : (h1s + (size_t)(t & 1) * BH);
      const u16* src1 = mySlot + (size_t)((t - 1) & 1) * BH;
      const u16* a0p = src0 + arow * 1024 + koff;
      const u16* a1p = src1 + arow * 1024 + koff;

      f32x4 acc0 = {0.f, 0.f, 0.f, 0.f};
      f32x4 acc1 = {0.f, 0.f, 0.f, 0.f};
      f32x4 acc2 = {0.f, 0.f, 0.f, 0.f};
      f32x4 acc3 = {0.f, 0.f, 0.f, 0.f};
#pragma unroll 16
      for (int kc = 0; kc < 32; ++kc) {     // input projection (x_t or h1_t)
        bf16x8 a  = *(const bf16x8*)(a0p + kc * 32);
        bf16x8 b0 = *(const bf16x8*)(bW0 + kc * 32);
        bf16x8 b1 = *(const bf16x8*)(bW1 + kc * 32);
        if (kc & 1) {
          acc2 = __builtin_amdgcn_mfma_f32_16x16x32_bf16(a, b0, acc2, 0, 0, 0);
          acc3 = __builtin_amdgcn_mfma_f32_16x16x32_bf16(a, b1, acc3, 0, 0, 0);
        } else {
          acc0 = __builtin_amdgcn_mfma_f32_16x16x32_bf16(a, b0, acc0, 0, 0, 0);
          acc1 = __builtin_amdgcn_mfma_f32_16x16x32_bf16(a, b1, acc1, 0, 0, 0);
        }
      }
#pragma unroll 16
      for (int kc = 0; kc < 32; ++kc) {     // recurrent projection (h_{t-1})
        bf16x8 a  = *(const bf16x8*)(a1p + kc * 32);
        bf16x8 b0 = *(const bf16x8*)(bH0 + kc * 32);
        bf16x8 b1 = *(const bf16x8*)(bH1 + kc * 32);
        if (kc & 1) {
          acc2 = __builtin_amdgcn_mfma_f32_16x16x32_bf16(a, b0, acc2, 0, 0, 0);
          acc3 = __builtin_amdgcn_mfma_f32_16x16x32_bf16(a, b1, acc3, 0, 0, 0);
        } else {
          acc0 = __builtin_amdgcn_mfma_f32_16x16x32_bf16(a, b0, acc0, 0, 0, 0);
          acc1 = __builtin_amdgcn_mfma_f32_16x16x32_bf16(a, b1, acc1, 0, 0, 0);
        }
      }

      float g0[4], g1[4], f4[4], o4[4];
#pragma unroll
      for (int r = 0; r < 4; ++r) { g0[r] = acc0[r] + acc2[r] + bn0; g1[r] = acc1[r] + acc3[r] + bn1; }
#pragma unroll
      for (int r = 0; r < 4; ++r) { f4[r] = __shfl_down(g0[r], 8); o4[r] = __shfl_down(g1[r], 8); }

      if (act) {
        float hn[4];
#pragma unroll
        for (int r = 0; r < 4; ++r) {
          float iv = sigm(g0[r]);           // cols 0..7   : i
          float fv = sigm(f4[r]);           // cols 8..15  : f (shuffled)
          float gv = tanh_fast(g1[r]);      // cols 16..23 : g
          float ov = sigm(o4[r]);           // cols 24..31 : o (shuffled)
          c[r] = fv * c[r] + iv * gv;
          hn[r] = ov * tanh_fast(c[r]);
        }
        u16* hdst = mySlot + (size_t)(t & 1) * BH;
#pragma unroll
        for (int r = 0; r < 4; ++r) hdst[(mrow0 + r) * 1024 + col] = f2bf(hn[r]);
        if (layer == 1) {
          float* od = out + (size_t)t * BH;
#pragma unroll
          for (int r = 0; r < 4; ++r) od[(mrow0 + r) * 1024 + col] = hn[r];
        }
        if (t == TT - 1) {
#pragma unroll
          for (int r = 0; r < 4; ++r) {
            out[OUT_HN + (size_t)layer * BH + (mrow0 + r) * 1024 + col] = hn[r];
            out[OUT_CN + (size_t)layer * BH + (mrow0 + r) * 1024 + col] = c[r];
          }
        }
      }
    }

    // ---- grid barrier: per-block flags + single release word, RELAXED polls,
    // exactly one release fence (wbl2) + one acquire fence (inv) per block-iter
    if (it < TT) {
      __syncthreads();                      // all waves' stores drained (vmcnt 0)
      if (bid == 0) {
        if (tid > 0) {                      // thread i waits for block i's arrival
          while (__hip_atomic_load(&flags[tid * 32], __ATOMIC_RELAXED,
                                   __HIP_MEMORY_SCOPE_AGENT) < it + 1)
            __builtin_amdgcn_s_sleep(1);
        }
        __syncthreads();                    // all arrivals seen
        if (tid == 0) {
          __builtin_amdgcn_fence(__ATOMIC_ACQ_REL, "agent");  // wbl2 own h + inv own caches
          __hip_atomic_store(rel, it + 1, __ATOMIC_RELAXED, __HIP_MEMORY_SCOPE_AGENT);
        }
        __syncthreads();
      } else {
        if (tid == 0) {
          __builtin_amdgcn_fence(__ATOMIC_RELEASE, "agent");  // writeback own h
          __hip_atomic_store(&flags[bid * 32], it + 1, __ATOMIC_RELAXED,
                             __HIP_MEMORY_SCOPE_AGENT);
          while (__hip_atomic_load(rel, __ATOMIC_RELAXED,
                                   __HIP_MEMORY_SCOPE_AGENT) < it + 1)
            __builtin_amdgcn_s_sleep(2);
          __builtin_amdgcn_fence(__ATOMIC_ACQUIRE, "agent");  // inv before reading new h
        }
        __syncthreads();
      }
    }
  }
}

extern "C" void kernel_launch(void* const* d_in, const int* in_sizes, int n_in,
                              void* d_out, int out_size, void* d_ws, size_t ws_size,
                              hipStream_t stream) {
  const float* x    = (const float*)d_in[0];
  const float* Wih  = (const float*)d_in[1];
  const float* Whh  = (const float*)d_in[2];
  const float* bias = (const float*)d_in[3];
  const float* h0   = (const float*)d_in[4];
  const float* c0   = (const float*)d_in[5];
  float* out = (float*)d_out;
  char* ws = (char*)d_ws;
  u16* xbf  = (u16*)(ws + WS_XBF);
  u16* h1s  = (u16*)(ws + WS_H1);
  u16* h2s  = (u16*)(ws + WS_H2);
  int* flags = (int*)(ws + WS_FLAGS);
  int* rel   = (int*)(ws + WS_REL);

  hipFuncSetAttribute((const void*)lstm_kernel,
                      hipFuncAttributeMaxDynamicSharedMemorySize, LDS_BYTES);

  cast_x_kernel<<<32768, 256, 0, stream>>>(x, xbf);
  init_kernel<<<512, 256, 0, stream>>>(h0, h1s, h2s, flags, rel);
  lstm_kernel<<<NBLK, 256, LDS_BYTES, stream>>>(Wih, Whh, bias, c0, xbf, h1s, h2s,
                                                out, flags, rel);
}

// Round 3
// 8830.833 us; speedup vs baseline: 2.4218x; 1.2573x over previous
//
#include <hip/hip_runtime.h>

#define TT 512
#define BH 65536            // B*H elements (64*1024)
#define NBLK 256

typedef unsigned short u16;
typedef __attribute__((ext_vector_type(8))) __bf16 bf16x8;
typedef __attribute__((ext_vector_type(4))) float f32x4;
typedef __attribute__((ext_vector_type(4))) float float4_t;
typedef __attribute__((ext_vector_type(2))) unsigned long long u64x2;

// workspace byte offsets
#define WS_XBF   0ull
#define WS_H1    67108864ull                 // x_bf16: 512*64*1024*2 B
#define WS_H2    (WS_H1 + 262144ull)         // 2 slots * 64*1024 * 2 B
#define WS_FLAGS (WS_H2 + 262144ull)         // 256 blocks * 32 ints (128 B apart)
#define WS_REL   (WS_FLAGS + 32768ull)       // release word, own line

#define LDS_BYTES 132096                     // 2 * 32 rows * 1032 elems * 2 B

__device__ __forceinline__ u16 f2bf(float f) {
  unsigned u = __builtin_bit_cast(unsigned, f);
  u += 0x7fffu + ((u >> 16) & 1u);
  return (u16)(u >> 16);
}

__device__ __forceinline__ float sigm(float x) { return 1.0f / (1.0f + __expf(-x)); }
__device__ __forceinline__ float tanh_fast(float x) { return 1.0f - 2.0f / (__expf(2.0f * x) + 1.0f); }

// 16B coherent read via two 8B agent-scope relaxed loads (global_load_dwordx2 sc1:
// bypasses the non-coherent per-XCD L2, reads the L3 coherence point directly)
__device__ __forceinline__ bf16x8 ld8_sc1(const u16* p) {
  u64x2 v;
  v.x = __hip_atomic_load((const unsigned long long*)p,       __ATOMIC_RELAXED, __HIP_MEMORY_SCOPE_AGENT);
  v.y = __hip_atomic_load((const unsigned long long*)(p + 4), __ATOMIC_RELAXED, __HIP_MEMORY_SCOPE_AGENT);
  return __builtin_bit_cast(bf16x8, v);
}

__global__ __launch_bounds__(256) void cast_x_kernel(const float* __restrict__ x, u16* __restrict__ xbf) {
  unsigned i = (blockIdx.x * 256u + threadIdx.x) * 4u;
  float4_t v = *(const float4_t*)(x + i);
  unsigned p0 = (unsigned)f2bf(v.x) | ((unsigned)f2bf(v.y) << 16);
  unsigned p1 = (unsigned)f2bf(v.z) | ((unsigned)f2bf(v.w) << 16);
  uint2 p; p.x = p0; p.y = p1;
  *(uint2*)(xbf + i) = p;
}

__global__ __launch_bounds__(256) void init_kernel(const float* __restrict__ h0,
                                                   u16* __restrict__ h1s, u16* __restrict__ h2s,
                                                   int* __restrict__ flags, int* __restrict__ rel) {
  unsigned idx = blockIdx.x * 256u + threadIdx.x;   // < 131072
  unsigned l = idx >> 16;
  unsigned pos = idx & 65535u;
  u16* dst = (l == 0 ? h1s : h2s) + BH + pos;       // slot 1 = "h[-1]"
  *dst = f2bf(h0[idx]);                             // end-of-kernel release flushes to L3
  if (idx < 8192) flags[idx] = 0;
  if (idx == 0) rel[0] = 0;
}

// 256 blocks: 0..127 layer0 (step t=it), 128..255 layer1 (step t=it-1).
// Each block: 8 hidden cols -> 32 gate cols, weights LDS-resident, c in regs.
// h exchanged through L3 via sc1 atomics -> NO agent fences anywhere.
__global__ __launch_bounds__(256, 1) void lstm_kernel(
    const float* __restrict__ Wih, const float* __restrict__ Whh,
    const float* __restrict__ bias, const float* __restrict__ c0,
    const u16* __restrict__ xbf,
    u16* __restrict__ h1s, u16* __restrict__ h2s,
    float* __restrict__ out, int* __restrict__ flags, int* __restrict__ rel)
{
  extern __shared__ __align__(16) char smem_raw[];
  u16* lw = (u16*)smem_raw;                 // Wih[32][1032] then Whh[32][1032]
  const int tid = threadIdx.x;
  const int bid = blockIdx.x;
  const int layer = bid >> 7;
  const int lb = bid & 127;
  const int jbase = lb * 8;

  // ---- stage weight slices into LDS (fp32 -> bf16), rows n = gate*8 + jj ----
  const float* WihL = Wih + (size_t)layer * 4096 * 1024;
  const float* WhhL = Whh + (size_t)layer * 4096 * 1024;
  for (int idx = tid; idx < 8192; idx += 256) {
    int n = idx >> 8;                       // 0..31
    int k4 = (idx & 255) * 4;
    int gate = n >> 3, jj = n & 7;
    size_t grow = (size_t)(gate * 1024 + jbase + jj) * 1024 + k4;
    float4_t a = *(const float4_t*)(WihL + grow);
    float4_t b = *(const float4_t*)(WhhL + grow);
    u16* d0 = lw + n * 1032 + k4;
    u16* d1 = lw + 33024 + n * 1032 + k4;   // Whh block at +32*1032
    d0[0] = f2bf(a.x); d0[1] = f2bf(a.y); d0[2] = f2bf(a.z); d0[3] = f2bf(a.w);
    d1[0] = f2bf(b.x); d1[1] = f2bf(b.y); d1[2] = f2bf(b.z); d1[3] = f2bf(b.w);
  }

  const int lane = tid & 63;
  const int w = tid >> 6;                   // wave id: M-tile
  const int q = lane >> 4;                  // quad
  const int ln = lane & 15;
  const int arow = w * 16 + ln;             // batch row for A-frag loads
  const int koff = q * 8;
  const int jj = ln & 7;
  const bool act = ln < 8;                  // epilogue-active lanes
  const int col = jbase + jj;               // hidden column
  const int mrow0 = w * 16 + q * 4;         // C-frag rows mrow0 + r

  const float* bL = bias + layer * 4096;
  const float bn0 = bL[(ln >> 3) * 1024 + jbase + jj];        // i/f bias (col n=ln)
  const float bn1 = bL[(2 + (ln >> 3)) * 1024 + jbase + jj];  // g/o bias (col n=16+ln)

  float c[4];
  {
    const float* c0L = c0 + (size_t)layer * BH;
#pragma unroll
    for (int r = 0; r < 4; ++r) c[r] = c0L[(mrow0 + r) * 1024 + col];
  }

  u16* mySlot = (layer == 0) ? h1s : h2s;
  const size_t OUT_HN = (size_t)TT * BH;
  const size_t OUT_CN = OUT_HN + 2 * BH;

  // per-lane LDS base pointers for B-fragments
  const u16* bW0 = lw + ln * 1032 + koff;          // Wih, N-tile 0 (gates i,f)
  const u16* bW1 = lw + (16 + ln) * 1032 + koff;   // Wih, N-tile 1 (gates g,o)
  const u16* bH0 = bW0 + 33024;                    // Whh
  const u16* bH1 = bW1 + 33024;

  __syncthreads();

  for (int it = 0; it <= TT; ++it) {
    const int t = (layer == 0) ? it : (it - 1);
    if (t >= 0 && t < TT) {
      const u16* a1p = mySlot + (size_t)((t - 1) & 1) * BH + arow * 1024 + koff;

      f32x4 acc0 = {0.f, 0.f, 0.f, 0.f};
      f32x4 acc1 = {0.f, 0.f, 0.f, 0.f};
      f32x4 acc2 = {0.f, 0.f, 0.f, 0.f};
      f32x4 acc3 = {0.f, 0.f, 0.f, 0.f};

      if (layer == 0) {                     // input projection from x: cacheable
        const u16* a0p = xbf + (size_t)t * BH + arow * 1024 + koff;
#pragma unroll 16
        for (int kc = 0; kc < 32; ++kc) {
          bf16x8 a  = *(const bf16x8*)(a0p + kc * 32);
          bf16x8 b0 = *(const bf16x8*)(bW0 + kc * 32);
          bf16x8 b1 = *(const bf16x8*)(bW1 + kc * 32);
          if (kc & 1) {
            acc2 = __builtin_amdgcn_mfma_f32_16x16x32_bf16(a, b0, acc2, 0, 0, 0);
            acc3 = __builtin_amdgcn_mfma_f32_16x16x32_bf16(a, b1, acc3, 0, 0, 0);
          } else {
            acc0 = __builtin_amdgcn_mfma_f32_16x16x32_bf16(a, b0, acc0, 0, 0, 0);
            acc1 = __builtin_amdgcn_mfma_f32_16x16x32_bf16(a, b1, acc1, 0, 0, 0);
          }
        }
      } else {                              // input projection from h1: coherent
        const u16* a0p = h1s + (size_t)(t & 1) * BH + arow * 1024 + koff;
#pragma unroll 16
        for (int kc = 0; kc < 32; ++kc) {
          bf16x8 a  = ld8_sc1(a0p + kc * 32);
          bf16x8 b0 = *(const bf16x8*)(bW0 + kc * 32);
          bf16x8 b1 = *(const bf16x8*)(bW1 + kc * 32);
          if (kc & 1) {
            acc2 = __builtin_amdgcn_mfma_f32_16x16x32_bf16(a, b0, acc2, 0, 0, 0);
            acc3 = __builtin_amdgcn_mfma_f32_16x16x32_bf16(a, b1, acc3, 0, 0, 0);
          } else {
            acc0 = __builtin_amdgcn_mfma_f32_16x16x32_bf16(a, b0, acc0, 0, 0, 0);
            acc1 = __builtin_amdgcn_mfma_f32_16x16x32_bf16(a, b1, acc1, 0, 0, 0);
          }
        }
      }
#pragma unroll 16
      for (int kc = 0; kc < 32; ++kc) {     // recurrent projection (own h, coherent)
        bf16x8 a  = ld8_sc1(a1p + kc * 32);
        bf16x8 b0 = *(const bf16x8*)(bH0 + kc * 32);
        bf16x8 b1 = *(const bf16x8*)(bH1 + kc * 32);
        if (kc & 1) {
          acc2 = __builtin_amdgcn_mfma_f32_16x16x32_bf16(a, b0, acc2, 0, 0, 0);
          acc3 = __builtin_amdgcn_mfma_f32_16x16x32_bf16(a, b1, acc3, 0, 0, 0);
        } else {
          acc0 = __builtin_amdgcn_mfma_f32_16x16x32_bf16(a, b0, acc0, 0, 0, 0);
          acc1 = __builtin_amdgcn_mfma_f32_16x16x32_bf16(a, b1, acc1, 0, 0, 0);
        }
      }

      float g0[4], g1[4], f4[4], o4[4];
#pragma unroll
      for (int r = 0; r < 4; ++r) { g0[r] = acc0[r] + acc2[r] + bn0; g1[r] = acc1[r] + acc3[r] + bn1; }
#pragma unroll
      for (int r = 0; r < 4; ++r) { f4[r] = __shfl_down(g0[r], 8); o4[r] = __shfl_down(g1[r], 8); }

      if (act) {
        float hn[4];
#pragma unroll
        for (int r = 0; r < 4; ++r) {
          float iv = sigm(g0[r]);           // cols 0..7   : i
          float fv = sigm(f4[r]);           // cols 8..15  : f (shuffled)
          float gv = tanh_fast(g1[r]);      // cols 16..23 : g
          float ov = sigm(o4[r]);           // cols 24..31 : o (shuffled)
          c[r] = fv * c[r] + iv * gv;
          hn[r] = ov * tanh_fast(c[r]);
        }
        u16* hdst = mySlot + (size_t)(t & 1) * BH;
#pragma unroll
        for (int r = 0; r < 4; ++r)         // write-through to L3 (sc1)
          __hip_atomic_store(&hdst[(mrow0 + r) * 1024 + col], f2bf(hn[r]),
                             __ATOMIC_RELAXED, __HIP_MEMORY_SCOPE_AGENT);
        if (layer == 1) {
          float* od = out + (size_t)t * BH;
#pragma unroll
          for (int r = 0; r < 4; ++r) od[(mrow0 + r) * 1024 + col] = hn[r];
        }
        if (t == TT - 1) {
#pragma unroll
          for (int r = 0; r < 4; ++r) {
            out[OUT_HN + (size_t)layer * BH + (mrow0 + r) * 1024 + col] = hn[r];
            out[OUT_CN + (size_t)layer * BH + (mrow0 + r) * 1024 + col] = c[r];
          }
        }
      }
    }

    // ---- grid barrier: flags + release word; NO agent fences. sc1 stores are
    // visible at L3 once vmcnt retires, which __syncthreads enforces.
    if (it < TT) {
      __syncthreads();
      if (bid == 0) {
        if (tid > 0) {
          while (__hip_atomic_load(&flags[tid * 32], __ATOMIC_RELAXED,
                                   __HIP_MEMORY_SCOPE_AGENT) < it + 1)
            __builtin_amdgcn_s_sleep(1);
        }
        __syncthreads();                    // all arrivals seen
        if (tid == 0)
          __hip_atomic_store(rel, it + 1, __ATOMIC_RELAXED, __HIP_MEMORY_SCOPE_AGENT);
      } else {
        if (tid == 0) {
          __hip_atomic_store(&flags[bid * 32], it + 1, __ATOMIC_RELAXED,
                             __HIP_MEMORY_SCOPE_AGENT);
          while (__hip_atomic_load(rel, __ATOMIC_RELAXED,
                                   __HIP_MEMORY_SCOPE_AGENT) < it + 1)
            __builtin_amdgcn_s_sleep(1);
        }
        __syncthreads();
      }
      // compiler-reorder guard only (workgroup scope: waitcnt, no cache ops)
      __builtin_amdgcn_fence(__ATOMIC_ACQUIRE, "workgroup");
    }
  }
}

extern "C" void kernel_launch(void* const* d_in, const int* in_sizes, int n_in,
                              void* d_out, int out_size, void* d_ws, size_t ws_size,
                              hipStream_t stream) {
  const float* x    = (const float*)d_in[0];
  const float* Wih  = (const float*)d_in[1];
  const float* Whh  = (const float*)d_in[2];
  const float* bias = (const float*)d_in[3];
  const float* h0   = (const float*)d_in[4];
  const float* c0   = (const float*)d_in[5];
  float* out = (float*)d_out;
  char* ws = (char*)d_ws;
  u16* xbf  = (u16*)(ws + WS_XBF);
  u16* h1s  = (u16*)(ws + WS_H1);
  u16* h2s  = (u16*)(ws + WS_H2);
  int* flags = (int*)(ws + WS_FLAGS);
  int* rel   = (int*)(ws + WS_REL);

  hipFuncSetAttribute((const void*)lstm_kernel,
                      hipFuncAttributeMaxDynamicSharedMemorySize, LDS_BYTES);

  cast_x_kernel<<<32768, 256, 0, stream>>>(x, xbf);
  init_kernel<<<512, 256, 0, stream>>>(h0, h1s, h2s, flags, rel);
  lstm_kernel<<<NBLK, 256, LDS_BYTES, stream>>>(Wih, Whh, bias, c0, xbf, h1s, h2s,
                                                out, flags, rel);
}